// Round 8
// baseline (297.427 us; speedup 1.0000x reference)
//
#include <hip/hip_runtime.h>

// GQA_22436909154699: softmax over a size-1 axis == 1.0, so the reference
// reduces to  out[bl, g*512+h*64+d] = (x @ Wkv + bkv)[bl, g*128+64+d].
// => one (16384 x 2048) @ (2048 x 256) GEMM (v-cols only) + broadcast x8.
// R8: TLP fix — BM 64->32 => 2048 blocks = 8 blocks/CU = 32 waves/CU.
// Depth-1 register prefetch (R7 showed depth-2 worth only 4%, and its
// VGPRs would halve occupancy); VGPR<=64 enforced via launch_bounds(256,8).

#define EMBED 2048
#define BM 32
#define BK 64
#define KIT (EMBED / BK)  // 32
#define SA 72             // LDS row stride in halfs (144 B, 16B-aligned)
#define SV 68             // epilogue V stride in floats

typedef _Float16 half8 __attribute__((ext_vector_type(8)));
typedef float f32x4 __attribute__((ext_vector_type(4)));

// lgkm-only barrier: LDS ordering enforced, global loads stay in flight.
#define BAR() asm volatile("s_waitcnt lgkmcnt(0)\ns_barrier" ::: "memory")

// ---- pre-pass: Bt[n][k] (f16) = Wkv[k][vcol(n)], vcol(n)=(n>>6)*128+64+(n&63)
__global__ __launch_bounds__(256) void prep_b(const float* __restrict__ Wkv,
                                              _Float16* __restrict__ Bt) {
  const int t = threadIdx.x;
  const int kb = blockIdx.x * 4;  // 512 blocks cover k = 0..2047
  const int vcol = ((t >> 6) * 128) + 64 + (t & 63);
  float v[4];
#pragma unroll
  for (int i = 0; i < 4; ++i) v[i] = Wkv[(size_t)(kb + i) * 512 + vcol];
  _Float16 h[4];
#pragma unroll
  for (int i = 0; i < 4; ++i) h[i] = (_Float16)v[i];
  *(float2*)&Bt[(size_t)t * EMBED + kb] = *(float2*)h;
}

// ---- main: block = 32m x 64n tile, K-loop over 32 slabs of 64.
__global__ __launch_bounds__(256, 8) void gqa_main(
    const float* __restrict__ x, const _Float16* __restrict__ Bt,
    const float* __restrict__ bkv, float* __restrict__ out) {
  __shared__ __align__(16) char smem[(BM + 64) * SA * 2];  // 13824 B
  _Float16* As = (_Float16*)smem;   // 32 x SA halfs
  _Float16* Bs = As + BM * SA;      // 64 x SA halfs
  float* Vs = (float*)smem;         // overlay: 32 x SV fp32 = 8704 B

  const int tid = threadIdx.x;
  const int wave = tid >> 6;
  const int lane = tid & 63;
  const int lm = lane & 15;
  const int lq = lane >> 4;
  // XCD swizzle: the 4 n-group blocks of one mb land on the same XCD (i%8).
  const int bi = blockIdx.x;
  const int nb = (bi >> 3) & 3;
  const int mb = ((bi >> 5) << 3) | (bi & 7);
  const int mi2 = wave & 1;   // wave's m-half (16 rows)
  const int ni2 = wave >> 1;  // wave's n-half (32 cols)

  // staging A: 32 rows x 64 fp32; thread t -> row t>>3, 8 floats at (t&7)*8
  const int ar = tid >> 3, ac = (tid & 7) * 8;
  const float* ap = x + (size_t)(mb * BM + ar) * EMBED + ac;
  _Float16* aw = As + ar * SA + ac;
  // staging B: 64 rows x 64 f16; thread t -> row t>>2, cols (t&3)*8 and +32
  const int br = tid >> 2, bc = (tid & 3) * 8;
  const _Float16* bp = Bt + (size_t)(nb * 64 + br) * EMBED + bc;
  _Float16* bw = Bs + br * SA + bc;

  // fragment read bases: A row = mi2*16 + lm ; B row = ni2*32 + ni*16 + lm
  const _Float16* ard = As + (mi2 * 16 + lm) * SA + lq * 8;
  const _Float16* brd = Bs + (ni2 * 32 + lm) * SA + lq * 8;

  f32x4 pa[2];   // 8 floats of A prefetch
  half8 pb[2];   // 16 halfs of B prefetch

#define LOADAB(kt)                              \
  {                                             \
    const float* p_ = ap + (kt) * BK;           \
    pa[0] = *(const f32x4*)p_;                  \
    pa[1] = *(const f32x4*)(p_ + 4);            \
    const _Float16* q_ = bp + (kt) * BK;        \
    pb[0] = *(const half8*)q_;                  \
    pb[1] = *(const half8*)(q_ + 32);           \
  }

  f32x4 acc[2] = {};

  LOADAB(0);
  for (int kt = 0; kt < KIT; ++kt) {
    // stage (waits vmcnt for this slab's loads, issued one full iter ago)
    half8 ha;
#pragma unroll
    for (int j = 0; j < 4; ++j) {
      ha[j] = (_Float16)pa[0][j];
      ha[4 + j] = (_Float16)pa[1][j];
    }
    *(half8*)aw = ha;        // one ds_write_b128
    *(half8*)bw = pb[0];
    *(half8*)(bw + 32) = pb[1];
    BAR();

    if (kt + 1 < KIT) LOADAB(kt + 1);  // in flight across compute + barrier

    half8 af[2], bf[2][2];
#pragma unroll
    for (int ks = 0; ks < 2; ++ks) af[ks] = *(const half8*)(ard + ks * 32);
#pragma unroll
    for (int ni = 0; ni < 2; ++ni)
#pragma unroll
      for (int ks = 0; ks < 2; ++ks)
        bf[ni][ks] = *(const half8*)(brd + ni * 16 * SA + ks * 32);
#pragma unroll
    for (int ni = 0; ni < 2; ++ni)
#pragma unroll
      for (int ks = 0; ks < 2; ++ks)
        acc[ni] = __builtin_amdgcn_mfma_f32_16x16x32_f16(af[ks], bf[ni][ks],
                                                         acc[ni], 0, 0, 0);
    BAR();  // all ds_reads done block-wide; next stores may proceed
  }

  // epilogue: bias + V(32x64) to LDS (C/D: col = lm, row = lq*4 + r)
#pragma unroll
  for (int ni = 0; ni < 2; ++ni) {
    const int nc = ni2 * 32 + ni * 16 + lm;
    const float bias = bkv[nb * 128 + 64 + nc];
    f32x4 v = acc[ni];
#pragma unroll
    for (int r = 0; r < 4; ++r) {
      Vs[(mi2 * 16 + lq * 4 + r) * SV + nc] = v[r] + bias;
    }
  }
  BAR();

  // broadcast: block writes out[mb*32 .. +32][nb*512 .. +512], coalesced
  f32x4* out4 = (f32x4*)(out + (size_t)(mb * BM) * EMBED + nb * 512);
#pragma unroll 8
  for (int i = 0; i < 16; ++i) {
    const int f = i * 256 + tid;  // 0..4095 over 32 rows x 128 float4
    const int row = f >> 7;
    const int c4 = f & 127;
    const int d4 = c4 & 15;
    out4[(size_t)row * 512 + c4] = *(const f32x4*)&Vs[row * SV + d4 * 4];
  }
}

extern "C" void kernel_launch(void* const* d_in, const int* in_sizes, int n_in,
                              void* d_out, int out_size, void* d_ws, size_t ws_size,
                              hipStream_t stream) {
  const float* x = (const float*)d_in[0];
  // d_in[1] = Wq, d_in[2] = bq : dead code (softmax over size-1 axis == 1)
  const float* Wkv = (const float*)d_in[3];
  const float* bkv = (const float*)d_in[4];
  float* out = (float*)d_out;
  _Float16* Bt = (_Float16*)d_ws;  // 256*2048 f16 = 1 MB scratch

  prep_b<<<512, 256, 0, stream>>>(Wkv, Bt);
  gqa_main<<<2048, 256, 0, stream>>>(x, Bt, bkv, out);
}